// Round 1
// baseline (1083.882 us; speedup 1.0000x reference)
//
#include <hip/hip_runtime.h>
#include <math.h>

// ---------------------------------------------------------------------------
// GCN-VAE fused pipeline for MI355X.
// N=50000 nodes, E=1.6M edges, F=H=128, L=64 (derived from in_sizes).
//
// Pipeline:
//   CSR build (histogram -> scan -> fill)      [per call; no persistent state]
//   Y1 = X @ W_enc                             (matmul, K=128, M=128)
//   h  = A*Y1 + b_enc                          (agg)
//   Ah = A*h                                   (agg)
//   mean = Ah @ W_mean + b_mean                (matmul, M=64) -> d_out
//   lv   = Ah @ W_lv   + b_lv                  (matmul, M=64) -> d_out
//   z = noise*exp(0.5*lv)+mean                 (elementwise)  -> d_out
//   Y2 = z @ W_d1                              (matmul, K=64, M=128)
//   hd = A*Y2 + b_d1                           (agg)
//   Y3 = hd @ W_d2                             (matmul, K=128, M=128)
//   out = A*Y3 + b_d2                          (agg) -> d_out
// ---------------------------------------------------------------------------

__global__ void zero_kernel(int* __restrict__ p, int n) {
    int i = blockIdx.x * blockDim.x + threadIdx.x;
    if (i < n) p[i] = 0;
}

__global__ void hist_kernel(const int* __restrict__ dst, int E,
                            int* __restrict__ count) {
    int e = blockIdx.x * blockDim.x + threadIdx.x;
    if (e < E) atomicAdd(&count[dst[e]], 1);
}

// Single-block exclusive scan over deg = count+1 (self-loop included).
// Also emits cursor copy and dinv = rsqrt(deg).
__global__ __launch_bounds__(1024) void scan_kernel(
    const int* __restrict__ count, int* __restrict__ offsets,
    int* __restrict__ cursor, float* __restrict__ dinv, int n) {
    const int T = 1024;
    __shared__ int sums[T];
    int tid = threadIdx.x;
    int chunk = (n + T - 1) / T;
    int start = tid * chunk;
    int end = start + chunk; if (end > n) end = n;
    int s = 0;
    for (int i = start; i < end; i++) s += count[i] + 1;
    sums[tid] = s;
    __syncthreads();
    // inclusive Hillis-Steele scan
    for (int off = 1; off < T; off <<= 1) {
        int v = (tid >= off) ? sums[tid - off] : 0;
        __syncthreads();
        sums[tid] += v;
        __syncthreads();
    }
    int run = (tid == 0) ? 0 : sums[tid - 1];
    for (int i = start; i < end; i++) {
        int deg = count[i] + 1;
        offsets[i] = run;
        cursor[i] = run;
        dinv[i] = rsqrtf((float)deg);
        run += deg;
    }
    if (tid == T - 1) offsets[n] = sums[T - 1];
}

// Scatter edges (and self-loops) into CSR-by-dst buckets. Stores src only;
// weights are recomputed in agg as dinv[dst]*dinv[src].
__global__ void fill_kernel(const int* __restrict__ src,
                            const int* __restrict__ dst, int E, int N,
                            int* __restrict__ cursor, int* __restrict__ esrc) {
    int e = blockIdx.x * blockDim.x + threadIdx.x;
    int total = E + N;
    if (e >= total) return;
    int s, d;
    if (e < E) { s = src[e]; d = dst[e]; }
    else       { s = e - E;  d = s; }
    int pos = atomicAdd(&cursor[d], 1);
    esrc[pos] = s;
}

// Tiled fp32 matmul: out[N,M] = X[N,K] @ W[K,M] (+ bias).
// Block = 256 threads; tile = 64 rows x 64 cols; each thread 4x4 outputs.
// grid = (ceil(N/64), M/64). LDS: W-tile 128x64 (32KB max) + X-tile 64xK (32KB max).
template <int K>
__global__ __launch_bounds__(256) void matmul_kernel(
    const float* __restrict__ X, const float* __restrict__ W, int M,
    const float* __restrict__ bias, float* __restrict__ out, int N) {
    __shared__ float ldsW[K][64];
    __shared__ float ldsX[64][K];
    int tid = threadIdx.x;
    int row0 = blockIdx.x * 64;
    int col0 = blockIdx.y * 64;

    // stage W column-tile
    for (int i = tid; i < K * 16; i += 256) {
        int k = i >> 4, j4 = i & 15;
        ((float4*)&ldsW[k][0])[j4] =
            *(const float4*)&W[(size_t)k * M + col0 + j4 * 4];
    }
    // stage X row-tile
    int maxr = N - row0; if (maxr > 64) maxr = 64;
    for (int i = tid; i < maxr * (K / 4); i += 256) {
        int r = i / (K / 4), k4 = i % (K / 4);
        ((float4*)&ldsX[r][0])[k4] =
            *(const float4*)&X[(size_t)(row0 + r) * K + k4 * 4];
    }
    __syncthreads();

    int cg = tid & 15;   // 16 col groups x 4 cols
    int rg = tid >> 4;   // 16 row groups x 4 rows
    int rbase = rg * 4, cbase = cg * 4;
    float acc[4][4] = {};
    for (int k = 0; k < K; k += 4) {
        float4 xv[4];
#pragma unroll
        for (int r = 0; r < 4; r++)
            xv[r] = *(const float4*)&ldsX[rbase + r][k];
        const float* xp = (const float*)xv;
#pragma unroll
        for (int kk = 0; kk < 4; kk++) {
            float4 wv = *(const float4*)&ldsW[k + kk][cbase];
#pragma unroll
            for (int r = 0; r < 4; r++) {
                float xs = xp[r * 4 + kk];
                acc[r][0] += xs * wv.x;
                acc[r][1] += xs * wv.y;
                acc[r][2] += xs * wv.z;
                acc[r][3] += xs * wv.w;
            }
        }
    }
    float4 bv = make_float4(0.f, 0.f, 0.f, 0.f);
    if (bias) bv = *(const float4*)&bias[col0 + cbase];
#pragma unroll
    for (int r = 0; r < 4; r++) {
        int row = row0 + rbase + r;
        if (row < N) {
            float4 o = make_float4(acc[r][0] + bv.x, acc[r][1] + bv.y,
                                   acc[r][2] + bv.z, acc[r][3] + bv.w);
            *(float4*)&out[(size_t)row * M + col0 + cbase] = o;
        }
    }
}

// Gather-side aggregation: one wave per dst node, lane owns 2 of 128 cols.
// out[d][:] = dinv[d] * sum_{s in in(d)} dinv[s] * Y[s][:]  (+ bias)
__global__ __launch_bounds__(256) void agg_kernel(
    const float* __restrict__ Y, const int* __restrict__ offsets,
    const int* __restrict__ esrc, const float* __restrict__ dinv,
    const float* __restrict__ bias, float* __restrict__ out, int N) {
    int wid = (blockIdx.x * blockDim.x + threadIdx.x) >> 6;
    int lane = threadIdx.x & 63;
    if (wid >= N) return;
    int beg = offsets[wid], end = offsets[wid + 1];
    const float2* Y2 = (const float2*)Y;
    float accx = 0.f, accy = 0.f;
    int e = beg;
    for (; e + 2 <= end; e += 2) {  // 2 gathers in flight per iteration
        int s0 = esrc[e], s1 = esrc[e + 1];
        float w0 = dinv[s0], w1 = dinv[s1];
        float2 v0 = Y2[(size_t)s0 * 64 + lane];
        float2 v1 = Y2[(size_t)s1 * 64 + lane];
        accx += w0 * v0.x + w1 * v1.x;
        accy += w0 * v0.y + w1 * v1.y;
    }
    if (e < end) {
        int s0 = esrc[e];
        float w0 = dinv[s0];
        float2 v0 = Y2[(size_t)s0 * 64 + lane];
        accx += w0 * v0.x;
        accy += w0 * v0.y;
    }
    float dd = dinv[wid];
    float bx = 0.f, by = 0.f;
    if (bias) { bx = bias[2 * lane]; by = bias[2 * lane + 1]; }
    float2 o = make_float2(accx * dd + bx, accy * dd + by);
    ((float2*)out)[(size_t)wid * 64 + lane] = o;
}

__global__ void z_kernel(const float* __restrict__ noise,
                         const float* __restrict__ mean,
                         const float* __restrict__ lv,
                         float* __restrict__ z, int n) {
    int i = blockIdx.x * blockDim.x + threadIdx.x;
    if (i < n) z[i] = noise[i] * expf(0.5f * lv[i]) + mean[i];
}

extern "C" void kernel_launch(void* const* d_in, const int* in_sizes, int n_in,
                              void* d_out, int out_size, void* d_ws,
                              size_t ws_size, hipStream_t stream) {
    const float* feature = (const float*)d_in[0];
    const int*   ei      = (const int*)d_in[1];
    const float* noise   = (const float*)d_in[2];
    const float* W_enc   = (const float*)d_in[3];
    const float* b_enc   = (const float*)d_in[4];
    const float* W_mean  = (const float*)d_in[5];
    const float* b_mean  = (const float*)d_in[6];
    const float* W_lv    = (const float*)d_in[7];
    const float* b_lv    = (const float*)d_in[8];
    const float* W_d1    = (const float*)d_in[9];
    const float* b_d1    = (const float*)d_in[10];
    const float* W_d2    = (const float*)d_in[11];
    const float* b_d2    = (const float*)d_in[12];

    int N = in_sizes[0] / 128;
    int E = in_sizes[1] / 2;

    float* z_out    = (float*)d_out;
    float* mean_out = z_out + (size_t)N * 64;
    float* lv_out   = z_out + (size_t)N * 128;
    float* gout     = z_out + (size_t)N * 192;

    char* ws = (char*)d_ws;
    float* bufA   = (float*)ws;  ws += (size_t)N * 128 * 4;
    float* bufB   = (float*)ws;  ws += (size_t)N * 128 * 4;
    int*   esrc   = (int*)ws;    ws += (size_t)(E + N) * 4;
    int*   count  = (int*)ws;    ws += (size_t)N * 4;
    int*   offs   = (int*)ws;    ws += (size_t)(N + 1) * 4;
    int*   cursor = (int*)ws;    ws += (size_t)N * 4;
    float* dinv   = (float*)ws;  ws += (size_t)N * 4;

    const int* src = ei;
    const int* dst = ei + E;

    // ---- CSR build ----
    zero_kernel<<<(N + 255) / 256, 256, 0, stream>>>(count, N);
    hist_kernel<<<(E + 255) / 256, 256, 0, stream>>>(dst, E, count);
    scan_kernel<<<1, 1024, 0, stream>>>(count, offs, cursor, dinv, N);
    fill_kernel<<<(E + N + 255) / 256, 256, 0, stream>>>(src, dst, E, N,
                                                         cursor, esrc);

    int gx = (N + 63) / 64;
    int aggBlocks = (int)(((size_t)N * 64 + 255) / 256);

    // ---- encoder ----
    matmul_kernel<128><<<dim3(gx, 2), 256, 0, stream>>>(feature, W_enc, 128,
                                                        nullptr, bufA, N);
    agg_kernel<<<aggBlocks, 256, 0, stream>>>(bufA, offs, esrc, dinv, b_enc,
                                              bufB, N);              // h
    agg_kernel<<<aggBlocks, 256, 0, stream>>>(bufB, offs, esrc, dinv, nullptr,
                                              bufA, N);              // Ah
    matmul_kernel<128><<<dim3(gx, 1), 256, 0, stream>>>(bufA, W_mean, 64,
                                                        b_mean, mean_out, N);
    matmul_kernel<128><<<dim3(gx, 1), 256, 0, stream>>>(bufA, W_lv, 64,
                                                        b_lv, lv_out, N);
    z_kernel<<<(int)(((size_t)N * 64 + 255) / 256), 256, 0, stream>>>(
        noise, mean_out, lv_out, z_out, N * 64);

    // ---- decoder ----
    matmul_kernel<64><<<dim3(gx, 2), 256, 0, stream>>>(z_out, W_d1, 128,
                                                       nullptr, bufB, N);
    agg_kernel<<<aggBlocks, 256, 0, stream>>>(bufB, offs, esrc, dinv, b_d1,
                                              bufA, N);              // hd
    matmul_kernel<128><<<dim3(gx, 2), 256, 0, stream>>>(bufA, W_d2, 128,
                                                        nullptr, bufB, N);
    agg_kernel<<<aggBlocks, 256, 0, stream>>>(bufB, offs, esrc, dinv, b_d2,
                                              gout, N);              // out
}

// Round 2
// 902.288 us; speedup vs baseline: 1.2013x; 1.2013x over previous
//
#include <hip/hip_runtime.h>
#include <math.h>

// ---------------------------------------------------------------------------
// GCN-VAE fused pipeline for MI355X.  R1: parallel coalesced CSR scan
// (was 134us single-block), fused mean/lv/z head, agg unroll-4.
// ---------------------------------------------------------------------------

__global__ void zero_kernel(int* __restrict__ p, int n) {
    int i = blockIdx.x * blockDim.x + threadIdx.x;
    if (i < n) p[i] = 0;
}

__global__ void hist_kernel(const int* __restrict__ dst, int E,
                            int* __restrict__ count) {
    int e = blockIdx.x * blockDim.x + threadIdx.x;
    if (e < E) atomicAdd(&count[dst[e]], 1);
}

// --- 3-stage parallel scan over deg = count[i]+1 ---------------------------
// Stage A: per-block (1024 elems) sums, coalesced.
__global__ __launch_bounds__(256) void block_sum_kernel(
    const int* __restrict__ count, int N, int* __restrict__ blockSums) {
    int base = blockIdx.x * 1024;
    int s = 0;
#pragma unroll
    for (int j = 0; j < 4; j++) {
        int i = base + j * 256 + threadIdx.x;
        if (i < N) s += count[i] + 1;
    }
#pragma unroll
    for (int off = 32; off; off >>= 1) s += __shfl_down(s, off, 64);
    __shared__ int ws[4];
    if ((threadIdx.x & 63) == 0) ws[threadIdx.x >> 6] = s;
    __syncthreads();
    if (threadIdx.x == 0)
        blockSums[blockIdx.x] = ws[0] + ws[1] + ws[2] + ws[3];
}

// Stage B: exclusive scan of <=256 block sums in one block; writes total.
__global__ __launch_bounds__(256) void scan_sums_kernel(
    const int* __restrict__ blockSums, int nb, int* __restrict__ blockOffs,
    int* __restrict__ offsets, int N) {
    __shared__ int lds[256];
    int tid = threadIdx.x;
    int v = (tid < nb) ? blockSums[tid] : 0;
    lds[tid] = v;
    __syncthreads();
    for (int off = 1; off < 256; off <<= 1) {
        int u = (tid >= off) ? lds[tid - off] : 0;
        __syncthreads();
        lds[tid] += u;
        __syncthreads();
    }
    if (tid < nb) blockOffs[tid] = lds[tid] - v;
    if (tid == 255) offsets[N] = lds[255];
}

// Stage C: per-block local scan + emit offsets/cursor/dinv, coalesced.
__global__ __launch_bounds__(256) void scan_emit_kernel(
    const int* __restrict__ count, const int* __restrict__ blockOffs, int N,
    int* __restrict__ offsets, int* __restrict__ cursor,
    float* __restrict__ dinv) {
    __shared__ int lds[1024];
    __shared__ int tsum[256];
    int tid = threadIdx.x;
    int base = blockIdx.x * 1024;
#pragma unroll
    for (int j = 0; j < 4; j++) {
        int i = base + j * 256 + tid;
        lds[j * 256 + tid] = (i < N) ? count[i] + 1 : 0;
    }
    __syncthreads();
    int4 q = ((const int4*)lds)[tid];   // 4 contiguous degs, ds_read_b128
    int s = q.x + q.y + q.z + q.w;
    tsum[tid] = s;
    __syncthreads();
    for (int off = 1; off < 256; off <<= 1) {
        int u = (tid >= off) ? tsum[tid - off] : 0;
        __syncthreads();
        tsum[tid] += u;
        __syncthreads();
    }
    int run = blockOffs[blockIdx.x] + ((tid > 0) ? tsum[tid - 1] : 0);
    int4 e;
    e.x = run;
    e.y = run + q.x;
    e.z = run + q.x + q.y;
    e.w = run + q.x + q.y + q.z;
    __syncthreads();
    ((int4*)lds)[tid] = e;
    __syncthreads();
#pragma unroll
    for (int j = 0; j < 4; j++) {
        int i = base + j * 256 + tid;
        if (i < N) {
            int o = lds[j * 256 + tid];
            offsets[i] = o;
            cursor[i] = o;
            dinv[i] = rsqrtf((float)(count[i] + 1));
        }
    }
}

// Scatter edges (and self-loops) into CSR-by-dst buckets.
__global__ void fill_kernel(const int* __restrict__ src,
                            const int* __restrict__ dst, int E, int N,
                            int* __restrict__ cursor, int* __restrict__ esrc) {
    int e = blockIdx.x * blockDim.x + threadIdx.x;
    int total = E + N;
    if (e >= total) return;
    int s, d;
    if (e < E) { s = src[e]; d = dst[e]; }
    else       { s = e - E;  d = s; }
    int pos = atomicAdd(&cursor[d], 1);
    esrc[pos] = s;
}

// Tiled fp32 matmul: out[N,M] = X[N,K] @ W[K,M] (+ bias).
template <int K>
__global__ __launch_bounds__(256) void matmul_kernel(
    const float* __restrict__ X, const float* __restrict__ W, int M,
    const float* __restrict__ bias, float* __restrict__ out, int N) {
    __shared__ float ldsW[K][64];
    __shared__ float ldsX[64][K];
    int tid = threadIdx.x;
    int row0 = blockIdx.x * 64;
    int col0 = blockIdx.y * 64;

    for (int i = tid; i < K * 16; i += 256) {
        int k = i >> 4, j4 = i & 15;
        ((float4*)&ldsW[k][0])[j4] =
            *(const float4*)&W[(size_t)k * M + col0 + j4 * 4];
    }
    int maxr = N - row0; if (maxr > 64) maxr = 64;
    for (int i = tid; i < maxr * (K / 4); i += 256) {
        int r = i / (K / 4), k4 = i % (K / 4);
        ((float4*)&ldsX[r][0])[k4] =
            *(const float4*)&X[(size_t)(row0 + r) * K + k4 * 4];
    }
    __syncthreads();

    int cg = tid & 15, rg = tid >> 4;
    int rbase = rg * 4, cbase = cg * 4;
    float acc[4][4] = {};
    for (int k = 0; k < K; k += 4) {
        float4 xv[4];
#pragma unroll
        for (int r = 0; r < 4; r++)
            xv[r] = *(const float4*)&ldsX[rbase + r][k];
        const float* xp = (const float*)xv;
#pragma unroll
        for (int kk = 0; kk < 4; kk++) {
            float4 wv = *(const float4*)&ldsW[k + kk][cbase];
#pragma unroll
            for (int r = 0; r < 4; r++) {
                float xs = xp[r * 4 + kk];
                acc[r][0] += xs * wv.x;
                acc[r][1] += xs * wv.y;
                acc[r][2] += xs * wv.z;
                acc[r][3] += xs * wv.w;
            }
        }
    }
    float4 bv = make_float4(0.f, 0.f, 0.f, 0.f);
    if (bias) bv = *(const float4*)&bias[col0 + cbase];
#pragma unroll
    for (int r = 0; r < 4; r++) {
        int row = row0 + rbase + r;
        if (row < N) {
            float4 o = make_float4(acc[r][0] + bv.x, acc[r][1] + bv.y,
                                   acc[r][2] + bv.z, acc[r][3] + bv.w);
            *(float4*)&out[(size_t)row * M + col0 + cbase] = o;
        }
    }
}

// Fused VAE head: mean = Ah@Wm+bm, lv = Ah@Wl+bl, z = noise*exp(.5lv)+mean.
// One block = 64 rows x 64 cols (full M=64 width). Wm/Wl share one LDS buf.
__global__ __launch_bounds__(256) void head_kernel(
    const float* __restrict__ Ah, const float* __restrict__ Wm,
    const float* __restrict__ bm, const float* __restrict__ Wl,
    const float* __restrict__ bl, const float* __restrict__ noise,
    float* __restrict__ mean, float* __restrict__ lv, float* __restrict__ z,
    int N) {
    __shared__ float ldsX[64][128];
    __shared__ float ldsW[128][64];
    int tid = threadIdx.x;
    int row0 = blockIdx.x * 64;
    int maxr = N - row0; if (maxr > 64) maxr = 64;

    for (int i = tid; i < maxr * 32; i += 256) {
        int r = i >> 5, k4 = i & 31;
        ((float4*)&ldsX[r][0])[k4] =
            ((const float4*)&Ah[(size_t)(row0 + r) * 128])[k4];
    }
    for (int i = tid; i < 128 * 16; i += 256) {
        int k = i >> 4, j4 = i & 15;
        ((float4*)&ldsW[k][0])[j4] = ((const float4*)&Wm[(size_t)k * 64])[j4];
    }
    __syncthreads();

    int cg = tid & 15, rg = tid >> 4;
    int rbase = rg * 4, cbase = cg * 4;
    float accM[4][4] = {}, accL[4][4] = {};

    for (int k = 0; k < 128; k += 4) {
        float4 xv[4];
#pragma unroll
        for (int r = 0; r < 4; r++)
            xv[r] = *(const float4*)&ldsX[rbase + r][k];
        const float* xp = (const float*)xv;
#pragma unroll
        for (int kk = 0; kk < 4; kk++) {
            float4 wv = *(const float4*)&ldsW[k + kk][cbase];
#pragma unroll
            for (int r = 0; r < 4; r++) {
                float xs = xp[r * 4 + kk];
                accM[r][0] += xs * wv.x;
                accM[r][1] += xs * wv.y;
                accM[r][2] += xs * wv.z;
                accM[r][3] += xs * wv.w;
            }
        }
    }
    __syncthreads();  // done reading Wm
    for (int i = tid; i < 128 * 16; i += 256) {
        int k = i >> 4, j4 = i & 15;
        ((float4*)&ldsW[k][0])[j4] = ((const float4*)&Wl[(size_t)k * 64])[j4];
    }
    __syncthreads();
    for (int k = 0; k < 128; k += 4) {
        float4 xv[4];
#pragma unroll
        for (int r = 0; r < 4; r++)
            xv[r] = *(const float4*)&ldsX[rbase + r][k];
        const float* xp = (const float*)xv;
#pragma unroll
        for (int kk = 0; kk < 4; kk++) {
            float4 wv = *(const float4*)&ldsW[k + kk][cbase];
#pragma unroll
            for (int r = 0; r < 4; r++) {
                float xs = xp[r * 4 + kk];
                accL[r][0] += xs * wv.x;
                accL[r][1] += xs * wv.y;
                accL[r][2] += xs * wv.z;
                accL[r][3] += xs * wv.w;
            }
        }
    }

    float4 bmv = *(const float4*)&bm[cbase];
    float4 blv = *(const float4*)&bl[cbase];
#pragma unroll
    for (int r = 0; r < 4; r++) {
        int row = row0 + rbase + r;
        if (row < N) {
            float4 m = make_float4(accM[r][0] + bmv.x, accM[r][1] + bmv.y,
                                   accM[r][2] + bmv.z, accM[r][3] + bmv.w);
            float4 l = make_float4(accL[r][0] + blv.x, accL[r][1] + blv.y,
                                   accL[r][2] + blv.z, accL[r][3] + blv.w);
            float4 nv = *(const float4*)&noise[(size_t)row * 64 + cbase];
            float4 zv = make_float4(nv.x * expf(0.5f * l.x) + m.x,
                                    nv.y * expf(0.5f * l.y) + m.y,
                                    nv.z * expf(0.5f * l.z) + m.z,
                                    nv.w * expf(0.5f * l.w) + m.w);
            *(float4*)&mean[(size_t)row * 64 + cbase] = m;
            *(float4*)&lv[(size_t)row * 64 + cbase] = l;
            *(float4*)&z[(size_t)row * 64 + cbase] = zv;
        }
    }
}

// Gather-side aggregation: one wave per dst node, lane owns 2 of 128 cols.
__global__ __launch_bounds__(256) void agg_kernel(
    const float* __restrict__ Y, const int* __restrict__ offsets,
    const int* __restrict__ esrc, const float* __restrict__ dinv,
    const float* __restrict__ bias, float* __restrict__ out, int N) {
    int wid = (blockIdx.x * blockDim.x + threadIdx.x) >> 6;
    int lane = threadIdx.x & 63;
    if (wid >= N) return;
    int beg = offsets[wid], end = offsets[wid + 1];
    const float2* Y2 = (const float2*)Y;
    float accx = 0.f, accy = 0.f;
    int e = beg;
    for (; e + 4 <= end; e += 4) {  // 4 gathers in flight
        int s0 = esrc[e], s1 = esrc[e + 1], s2 = esrc[e + 2], s3 = esrc[e + 3];
        float w0 = dinv[s0], w1 = dinv[s1], w2 = dinv[s2], w3 = dinv[s3];
        float2 v0 = Y2[(size_t)s0 * 64 + lane];
        float2 v1 = Y2[(size_t)s1 * 64 + lane];
        float2 v2 = Y2[(size_t)s2 * 64 + lane];
        float2 v3 = Y2[(size_t)s3 * 64 + lane];
        accx += w0 * v0.x + w1 * v1.x + w2 * v2.x + w3 * v3.x;
        accy += w0 * v0.y + w1 * v1.y + w2 * v2.y + w3 * v3.y;
    }
    for (; e < end; e++) {
        int s0 = esrc[e];
        float w0 = dinv[s0];
        float2 v0 = Y2[(size_t)s0 * 64 + lane];
        accx += w0 * v0.x;
        accy += w0 * v0.y;
    }
    float dd = dinv[wid];
    float bx = 0.f, by = 0.f;
    if (bias) { bx = bias[2 * lane]; by = bias[2 * lane + 1]; }
    float2 o = make_float2(accx * dd + bx, accy * dd + by);
    ((float2*)out)[(size_t)wid * 64 + lane] = o;
}

extern "C" void kernel_launch(void* const* d_in, const int* in_sizes, int n_in,
                              void* d_out, int out_size, void* d_ws,
                              size_t ws_size, hipStream_t stream) {
    const float* feature = (const float*)d_in[0];
    const int*   ei      = (const int*)d_in[1];
    const float* noise   = (const float*)d_in[2];
    const float* W_enc   = (const float*)d_in[3];
    const float* b_enc   = (const float*)d_in[4];
    const float* W_mean  = (const float*)d_in[5];
    const float* b_mean  = (const float*)d_in[6];
    const float* W_lv    = (const float*)d_in[7];
    const float* b_lv    = (const float*)d_in[8];
    const float* W_d1    = (const float*)d_in[9];
    const float* b_d1    = (const float*)d_in[10];
    const float* W_d2    = (const float*)d_in[11];
    const float* b_d2    = (const float*)d_in[12];

    int N = in_sizes[0] / 128;
    int E = in_sizes[1] / 2;

    float* z_out    = (float*)d_out;
    float* mean_out = z_out + (size_t)N * 64;
    float* lv_out   = z_out + (size_t)N * 128;
    float* gout     = z_out + (size_t)N * 192;

    char* ws = (char*)d_ws;
    float* bufA    = (float*)ws;  ws += (size_t)N * 128 * 4;
    float* bufB    = (float*)ws;  ws += (size_t)N * 128 * 4;
    int*   esrc    = (int*)ws;    ws += (size_t)(E + N) * 4;
    int*   count   = (int*)ws;    ws += (size_t)N * 4;
    int*   offs    = (int*)ws;    ws += (size_t)(N + 1) * 4;
    int*   cursor  = (int*)ws;    ws += (size_t)N * 4;
    float* dinv    = (float*)ws;  ws += (size_t)N * 4;
    int*   bsums   = (int*)ws;    ws += 256 * 4;
    int*   boffs   = (int*)ws;    ws += 256 * 4;

    const int* src = ei;
    const int* dst = ei + E;

    int nb = (N + 1023) / 1024;   // scan blocks (49 for N=50000)

    // ---- CSR build ----
    zero_kernel<<<(N + 255) / 256, 256, 0, stream>>>(count, N);
    hist_kernel<<<(E + 255) / 256, 256, 0, stream>>>(dst, E, count);
    block_sum_kernel<<<nb, 256, 0, stream>>>(count, N, bsums);
    scan_sums_kernel<<<1, 256, 0, stream>>>(bsums, nb, boffs, offs, N);
    scan_emit_kernel<<<nb, 256, 0, stream>>>(count, boffs, N, offs, cursor,
                                             dinv);
    fill_kernel<<<(E + N + 255) / 256, 256, 0, stream>>>(src, dst, E, N,
                                                         cursor, esrc);

    int gx = (N + 63) / 64;
    int aggBlocks = (int)(((size_t)N * 64 + 255) / 256);

    // ---- encoder ----
    matmul_kernel<128><<<dim3(gx, 2), 256, 0, stream>>>(feature, W_enc, 128,
                                                        nullptr, bufA, N);
    agg_kernel<<<aggBlocks, 256, 0, stream>>>(bufA, offs, esrc, dinv, b_enc,
                                              bufB, N);              // h
    agg_kernel<<<aggBlocks, 256, 0, stream>>>(bufB, offs, esrc, dinv, nullptr,
                                              bufA, N);              // Ah
    head_kernel<<<gx, 256, 0, stream>>>(bufA, W_mean, b_mean, W_lv, b_lv,
                                        noise, mean_out, lv_out, z_out, N);

    // ---- decoder ----
    matmul_kernel<64><<<dim3(gx, 2), 256, 0, stream>>>(z_out, W_d1, 128,
                                                       nullptr, bufB, N);
    agg_kernel<<<aggBlocks, 256, 0, stream>>>(bufB, offs, esrc, dinv, b_d1,
                                              bufA, N);              // hd
    matmul_kernel<128><<<dim3(gx, 2), 256, 0, stream>>>(bufA, W_d2, 128,
                                                        nullptr, bufB, N);
    agg_kernel<<<aggBlocks, 256, 0, stream>>>(bufB, offs, esrc, dinv, b_d2,
                                              gout, N);              // out
}

// Round 3
// 671.374 us; speedup vs baseline: 1.6144x; 1.3439x over previous
//
#include <hip/hip_runtime.h>
#include <math.h>

// ---------------------------------------------------------------------------
// GCN-VAE fused pipeline for MI355X.
// R2: XCD-grouped fill/hist (kills 16x write amplification of random 4B
// scatters), bf16 intermediate feature buffers (halves agg gather traffic).
// ---------------------------------------------------------------------------

__device__ inline float bf2f(unsigned int lo16) {
    return __uint_as_float(lo16 << 16);
}
__device__ inline unsigned short f2bf(float f) {
    unsigned int u = __float_as_uint(f);
    return (unsigned short)((u + 0x7FFFu + ((u >> 16) & 1u)) >> 16);
}

__global__ void zero_kernel(int* __restrict__ p, int n) {
    int i = blockIdx.x * blockDim.x + threadIdx.x;
    if (i < n) p[i] = 0;
}

// XCD-grouped histogram: group g (= blockIdx&7, matching round-robin
// block->XCD mapping) only counts dst in its N/8 slice -> XCD-local atomics.
__global__ __launch_bounds__(256) void hist_kernel(
    const int* __restrict__ dst, int E, int N, int* __restrict__ count) {
    int group = blockIdx.x & 7;
    int bi = blockIdx.x >> 3;
    int nb = gridDim.x >> 3;
    int lo = (int)((long long)group * N / 8);
    int hi = (int)((long long)(group + 1) * N / 8);
    for (int e = bi * 256 + threadIdx.x; e < E; e += nb * 256) {
        int d = dst[e];
        if (d >= lo && d < hi) atomicAdd(&count[d], 1);
    }
}

// --- 3-stage parallel scan over deg = count[i]+1 ---------------------------
__global__ __launch_bounds__(256) void block_sum_kernel(
    const int* __restrict__ count, int N, int* __restrict__ blockSums) {
    int base = blockIdx.x * 1024;
    int s = 0;
#pragma unroll
    for (int j = 0; j < 4; j++) {
        int i = base + j * 256 + threadIdx.x;
        if (i < N) s += count[i] + 1;
    }
#pragma unroll
    for (int off = 32; off; off >>= 1) s += __shfl_down(s, off, 64);
    __shared__ int ws[4];
    if ((threadIdx.x & 63) == 0) ws[threadIdx.x >> 6] = s;
    __syncthreads();
    if (threadIdx.x == 0)
        blockSums[blockIdx.x] = ws[0] + ws[1] + ws[2] + ws[3];
}

__global__ __launch_bounds__(256) void scan_sums_kernel(
    const int* __restrict__ blockSums, int nb, int* __restrict__ blockOffs,
    int* __restrict__ offsets, int N) {
    __shared__ int lds[256];
    int tid = threadIdx.x;
    int v = (tid < nb) ? blockSums[tid] : 0;
    lds[tid] = v;
    __syncthreads();
    for (int off = 1; off < 256; off <<= 1) {
        int u = (tid >= off) ? lds[tid - off] : 0;
        __syncthreads();
        lds[tid] += u;
        __syncthreads();
    }
    if (tid < nb) blockOffs[tid] = lds[tid] - v;
    if (tid == 255) offsets[N] = lds[255];
}

__global__ __launch_bounds__(256) void scan_emit_kernel(
    const int* __restrict__ count, const int* __restrict__ blockOffs, int N,
    int* __restrict__ offsets, int* __restrict__ cursor,
    float* __restrict__ dinv) {
    __shared__ int lds[1024];
    __shared__ int tsum[256];
    int tid = threadIdx.x;
    int base = blockIdx.x * 1024;
#pragma unroll
    for (int j = 0; j < 4; j++) {
        int i = base + j * 256 + tid;
        lds[j * 256 + tid] = (i < N) ? count[i] + 1 : 0;
    }
    __syncthreads();
    int4 q = ((const int4*)lds)[tid];
    int s = q.x + q.y + q.z + q.w;
    tsum[tid] = s;
    __syncthreads();
    for (int off = 1; off < 256; off <<= 1) {
        int u = (tid >= off) ? tsum[tid - off] : 0;
        __syncthreads();
        tsum[tid] += u;
        __syncthreads();
    }
    int run = blockOffs[blockIdx.x] + ((tid > 0) ? tsum[tid - 1] : 0);
    int4 e;
    e.x = run;
    e.y = run + q.x;
    e.z = run + q.x + q.y;
    e.w = run + q.x + q.y + q.z;
    __syncthreads();
    ((int4*)lds)[tid] = e;
    __syncthreads();
#pragma unroll
    for (int j = 0; j < 4; j++) {
        int i = base + j * 256 + tid;
        if (i < N) {
            int o = lds[j * 256 + tid];
            offsets[i] = o;
            cursor[i] = o;
            dinv[i] = rsqrtf((float)(count[i] + 1));
        }
    }
}

// XCD-grouped CSR fill: group g only scatters edges with dst in its slice,
// so each XCD's random 4B writes stay inside a private ~(E+N)/8*4B region
// that lives in its own L2 -> lines go back to HBM fully dirty (no 16x amp).
__global__ __launch_bounds__(256) void fill_kernel(
    const int* __restrict__ src, const int* __restrict__ dst, int E, int N,
    int* __restrict__ cursor, int* __restrict__ esrc) {
    int group = blockIdx.x & 7;
    int bi = blockIdx.x >> 3;
    int nb = gridDim.x >> 3;
    int lo = (int)((long long)group * N / 8);
    int hi = (int)((long long)(group + 1) * N / 8);
    int total = E + N;
    for (int e = bi * 256 + threadIdx.x; e < total; e += nb * 256) {
        int s, d;
        if (e < E) {
            d = dst[e];
            if (d < lo || d >= hi) continue;
            s = src[e];
        } else {
            s = e - E;
            d = s;
            if (d < lo || d >= hi) continue;
        }
        int pos = atomicAdd(&cursor[d], 1);
        esrc[pos] = s;
    }
}

// Tiled matmul: out[N,M=128] = X[N,K] @ W[K,128], output bf16 (no bias --
// biases are folded into the following agg). XBF: X is bf16.
template <int K, bool XBF>
__global__ __launch_bounds__(256) void matmul_kernel(
    const void* __restrict__ Xv, const float* __restrict__ W,
    unsigned short* __restrict__ out, int N) {
    const int M = 128;
    __shared__ float ldsW[K][64];
    __shared__ float ldsX[64][K];
    int tid = threadIdx.x;
    int row0 = blockIdx.x * 64;
    int col0 = blockIdx.y * 64;

    for (int i = tid; i < K * 16; i += 256) {
        int k = i >> 4, j4 = i & 15;
        ((float4*)&ldsW[k][0])[j4] =
            *(const float4*)&W[(size_t)k * M + col0 + j4 * 4];
    }
    int maxr = N - row0; if (maxr > 64) maxr = 64;
    if (XBF) {
        const unsigned short* X = (const unsigned short*)Xv;
        for (int i = tid; i < maxr * (K / 8); i += 256) {
            int r = i / (K / 8), c8 = i % (K / 8);
            uint4 u = *(const uint4*)&X[(size_t)(row0 + r) * K + c8 * 8];
            float* dp = &ldsX[r][c8 * 8];
            dp[0] = bf2f(u.x & 0xFFFF); dp[1] = bf2f(u.x >> 16);
            dp[2] = bf2f(u.y & 0xFFFF); dp[3] = bf2f(u.y >> 16);
            dp[4] = bf2f(u.z & 0xFFFF); dp[5] = bf2f(u.z >> 16);
            dp[6] = bf2f(u.w & 0xFFFF); dp[7] = bf2f(u.w >> 16);
        }
    } else {
        const float* X = (const float*)Xv;
        for (int i = tid; i < maxr * (K / 4); i += 256) {
            int r = i / (K / 4), k4 = i % (K / 4);
            ((float4*)&ldsX[r][0])[k4] =
                *(const float4*)&X[(size_t)(row0 + r) * K + k4 * 4];
        }
    }
    __syncthreads();

    int cg = tid & 15, rg = tid >> 4;
    int rbase = rg * 4, cbase = cg * 4;
    float acc[4][4] = {};
    for (int k = 0; k < K; k += 4) {
        float4 xv[4];
#pragma unroll
        for (int r = 0; r < 4; r++)
            xv[r] = *(const float4*)&ldsX[rbase + r][k];
        const float* xp = (const float*)xv;
#pragma unroll
        for (int kk = 0; kk < 4; kk++) {
            float4 wv = *(const float4*)&ldsW[k + kk][cbase];
#pragma unroll
            for (int r = 0; r < 4; r++) {
                float xs = xp[r * 4 + kk];
                acc[r][0] += xs * wv.x;
                acc[r][1] += xs * wv.y;
                acc[r][2] += xs * wv.z;
                acc[r][3] += xs * wv.w;
            }
        }
    }
#pragma unroll
    for (int r = 0; r < 4; r++) {
        int row = row0 + rbase + r;
        if (row < N) {
            ushort4 o;
            o.x = f2bf(acc[r][0]); o.y = f2bf(acc[r][1]);
            o.z = f2bf(acc[r][2]); o.w = f2bf(acc[r][3]);
            *(ushort4*)&out[(size_t)row * M + col0 + cbase] = o;
        }
    }
}

// Fused VAE head: mean = Ah@Wm+bm, lv = Ah@Wl+bl, z = noise*exp(.5lv)+mean.
// Ah is bf16 [N,128]. Writes mean/lv/z fp32 (outputs) + z bf16 (for W_d1).
__global__ __launch_bounds__(256) void head_kernel(
    const unsigned short* __restrict__ Ah, const float* __restrict__ Wm,
    const float* __restrict__ bm, const float* __restrict__ Wl,
    const float* __restrict__ bl, const float* __restrict__ noise,
    float* __restrict__ mean, float* __restrict__ lv, float* __restrict__ z,
    unsigned short* __restrict__ zb, int N) {
    __shared__ float ldsX[64][128];
    __shared__ float ldsW[128][64];
    int tid = threadIdx.x;
    int row0 = blockIdx.x * 64;
    int maxr = N - row0; if (maxr > 64) maxr = 64;

    for (int i = tid; i < maxr * 16; i += 256) {
        int r = i >> 4, c8 = i & 15;
        uint4 u = *(const uint4*)&Ah[(size_t)(row0 + r) * 128 + c8 * 8];
        float* dp = &ldsX[r][c8 * 8];
        dp[0] = bf2f(u.x & 0xFFFF); dp[1] = bf2f(u.x >> 16);
        dp[2] = bf2f(u.y & 0xFFFF); dp[3] = bf2f(u.y >> 16);
        dp[4] = bf2f(u.z & 0xFFFF); dp[5] = bf2f(u.z >> 16);
        dp[6] = bf2f(u.w & 0xFFFF); dp[7] = bf2f(u.w >> 16);
    }
    for (int i = tid; i < 128 * 16; i += 256) {
        int k = i >> 4, j4 = i & 15;
        ((float4*)&ldsW[k][0])[j4] = ((const float4*)&Wm[(size_t)k * 64])[j4];
    }
    __syncthreads();

    int cg = tid & 15, rg = tid >> 4;
    int rbase = rg * 4, cbase = cg * 4;
    float accM[4][4] = {}, accL[4][4] = {};

    for (int k = 0; k < 128; k += 4) {
        float4 xv[4];
#pragma unroll
        for (int r = 0; r < 4; r++)
            xv[r] = *(const float4*)&ldsX[rbase + r][k];
        const float* xp = (const float*)xv;
#pragma unroll
        for (int kk = 0; kk < 4; kk++) {
            float4 wv = *(const float4*)&ldsW[k + kk][cbase];
#pragma unroll
            for (int r = 0; r < 4; r++) {
                float xs = xp[r * 4 + kk];
                accM[r][0] += xs * wv.x;
                accM[r][1] += xs * wv.y;
                accM[r][2] += xs * wv.z;
                accM[r][3] += xs * wv.w;
            }
        }
    }
    __syncthreads();
    for (int i = tid; i < 128 * 16; i += 256) {
        int k = i >> 4, j4 = i & 15;
        ((float4*)&ldsW[k][0])[j4] = ((const float4*)&Wl[(size_t)k * 64])[j4];
    }
    __syncthreads();
    for (int k = 0; k < 128; k += 4) {
        float4 xv[4];
#pragma unroll
        for (int r = 0; r < 4; r++)
            xv[r] = *(const float4*)&ldsX[rbase + r][k];
        const float* xp = (const float*)xv;
#pragma unroll
        for (int kk = 0; kk < 4; kk++) {
            float4 wv = *(const float4*)&ldsW[k + kk][cbase];
#pragma unroll
            for (int r = 0; r < 4; r++) {
                float xs = xp[r * 4 + kk];
                accL[r][0] += xs * wv.x;
                accL[r][1] += xs * wv.y;
                accL[r][2] += xs * wv.z;
                accL[r][3] += xs * wv.w;
            }
        }
    }

    float4 bmv = *(const float4*)&bm[cbase];
    float4 blv = *(const float4*)&bl[cbase];
#pragma unroll
    for (int r = 0; r < 4; r++) {
        int row = row0 + rbase + r;
        if (row < N) {
            float4 m = make_float4(accM[r][0] + bmv.x, accM[r][1] + bmv.y,
                                   accM[r][2] + bmv.z, accM[r][3] + bmv.w);
            float4 l = make_float4(accL[r][0] + blv.x, accL[r][1] + blv.y,
                                   accL[r][2] + blv.z, accL[r][3] + blv.w);
            float4 nv = *(const float4*)&noise[(size_t)row * 64 + cbase];
            float4 zv = make_float4(nv.x * expf(0.5f * l.x) + m.x,
                                    nv.y * expf(0.5f * l.y) + m.y,
                                    nv.z * expf(0.5f * l.z) + m.z,
                                    nv.w * expf(0.5f * l.w) + m.w);
            *(float4*)&mean[(size_t)row * 64 + cbase] = m;
            *(float4*)&lv[(size_t)row * 64 + cbase] = l;
            *(float4*)&z[(size_t)row * 64 + cbase] = zv;
            ushort4 zq;
            zq.x = f2bf(zv.x); zq.y = f2bf(zv.y);
            zq.z = f2bf(zv.z); zq.w = f2bf(zv.w);
            *(ushort4*)&zb[(size_t)row * 64 + cbase] = zq;
        }
    }
}

// Gather-side aggregation over bf16 rows (accumulate fp32).
// One wave per dst node; lane owns cols {2*lane, 2*lane+1}.
template <bool OUTBF>
__global__ __launch_bounds__(256) void agg_kernel(
    const unsigned short* __restrict__ Y, const int* __restrict__ offsets,
    const int* __restrict__ esrc, const float* __restrict__ dinv,
    const float* __restrict__ bias, void* __restrict__ outv, int N) {
    int wid = (blockIdx.x * blockDim.x + threadIdx.x) >> 6;
    int lane = threadIdx.x & 63;
    if (wid >= N) return;
    int beg = offsets[wid], end = offsets[wid + 1];
    const unsigned int* Yu = (const unsigned int*)Y;  // ushort2 pairs
    float ax = 0.f, ay = 0.f;
    int e = beg;
    for (; e + 4 <= end; e += 4) {  // 4 gathers in flight
        int s0 = esrc[e], s1 = esrc[e + 1], s2 = esrc[e + 2], s3 = esrc[e + 3];
        float w0 = dinv[s0], w1 = dinv[s1], w2 = dinv[s2], w3 = dinv[s3];
        unsigned int v0 = Yu[(size_t)s0 * 64 + lane];
        unsigned int v1 = Yu[(size_t)s1 * 64 + lane];
        unsigned int v2 = Yu[(size_t)s2 * 64 + lane];
        unsigned int v3 = Yu[(size_t)s3 * 64 + lane];
        ax += w0 * __uint_as_float(v0 << 16) + w1 * __uint_as_float(v1 << 16) +
              w2 * __uint_as_float(v2 << 16) + w3 * __uint_as_float(v3 << 16);
        ay += w0 * __uint_as_float(v0 & 0xFFFF0000u) +
              w1 * __uint_as_float(v1 & 0xFFFF0000u) +
              w2 * __uint_as_float(v2 & 0xFFFF0000u) +
              w3 * __uint_as_float(v3 & 0xFFFF0000u);
    }
    for (; e < end; e++) {
        int s0 = esrc[e];
        float w0 = dinv[s0];
        unsigned int v0 = Yu[(size_t)s0 * 64 + lane];
        ax += w0 * __uint_as_float(v0 << 16);
        ay += w0 * __uint_as_float(v0 & 0xFFFF0000u);
    }
    float dd = dinv[wid];
    float rx = ax * dd, ry = ay * dd;
    if (bias) { rx += bias[2 * lane]; ry += bias[2 * lane + 1]; }
    if (OUTBF) {
        unsigned int packed = (unsigned int)f2bf(rx) |
                              ((unsigned int)f2bf(ry) << 16);
        ((unsigned int*)outv)[(size_t)wid * 64 + lane] = packed;
    } else {
        ((float2*)outv)[(size_t)wid * 64 + lane] = make_float2(rx, ry);
    }
}

extern "C" void kernel_launch(void* const* d_in, const int* in_sizes, int n_in,
                              void* d_out, int out_size, void* d_ws,
                              size_t ws_size, hipStream_t stream) {
    const float* feature = (const float*)d_in[0];
    const int*   ei      = (const int*)d_in[1];
    const float* noise   = (const float*)d_in[2];
    const float* W_enc   = (const float*)d_in[3];
    const float* b_enc   = (const float*)d_in[4];
    const float* W_mean  = (const float*)d_in[5];
    const float* b_mean  = (const float*)d_in[6];
    const float* W_lv    = (const float*)d_in[7];
    const float* b_lv    = (const float*)d_in[8];
    const float* W_d1    = (const float*)d_in[9];
    const float* b_d1    = (const float*)d_in[10];
    const float* W_d2    = (const float*)d_in[11];
    const float* b_d2    = (const float*)d_in[12];

    int N = in_sizes[0] / 128;
    int E = in_sizes[1] / 2;

    float* z_out    = (float*)d_out;
    float* mean_out = z_out + (size_t)N * 64;
    float* lv_out   = z_out + (size_t)N * 128;
    float* gout     = z_out + (size_t)N * 192;

    char* ws = (char*)d_ws;
    unsigned short* Ybf = (unsigned short*)ws; ws += (size_t)N * 128 * 2;
    unsigned short* Hbf = (unsigned short*)ws; ws += (size_t)N * 128 * 2;
    unsigned short* Zbf = (unsigned short*)ws; ws += (size_t)N * 64 * 2;
    int*   esrc    = (int*)ws;   ws += (size_t)(E + N) * 4;
    int*   count   = (int*)ws;   ws += (size_t)N * 4;
    int*   offs    = (int*)ws;   ws += (size_t)(N + 1) * 4;
    int*   cursor  = (int*)ws;   ws += (size_t)N * 4;
    float* dinv    = (float*)ws; ws += (size_t)N * 4;
    int*   bsums   = (int*)ws;   ws += 256 * 4;
    int*   boffs   = (int*)ws;   ws += 256 * 4;

    const int* src = ei;
    const int* dst = ei + E;

    int nb = (N + 1023) / 1024;

    // ---- CSR build ----
    zero_kernel<<<(N + 255) / 256, 256, 0, stream>>>(count, N);
    hist_kernel<<<4096, 256, 0, stream>>>(dst, E, N, count);
    block_sum_kernel<<<nb, 256, 0, stream>>>(count, N, bsums);
    scan_sums_kernel<<<1, 256, 0, stream>>>(bsums, nb, boffs, offs, N);
    scan_emit_kernel<<<nb, 256, 0, stream>>>(count, boffs, N, offs, cursor,
                                             dinv);
    fill_kernel<<<4096, 256, 0, stream>>>(src, dst, E, N, cursor, esrc);

    int gx = (N + 63) / 64;
    int aggBlocks = (int)(((size_t)N * 64 + 255) / 256);

    // ---- encoder ----
    matmul_kernel<128, false><<<dim3(gx, 2), 256, 0, stream>>>(feature, W_enc,
                                                               Ybf, N);
    agg_kernel<true><<<aggBlocks, 256, 0, stream>>>(Ybf, offs, esrc, dinv,
                                                    b_enc, Hbf, N);   // h
    agg_kernel<true><<<aggBlocks, 256, 0, stream>>>(Hbf, offs, esrc, dinv,
                                                    nullptr, Ybf, N); // Ah
    head_kernel<<<gx, 256, 0, stream>>>(Ybf, W_mean, b_mean, W_lv, b_lv,
                                        noise, mean_out, lv_out, z_out, Zbf,
                                        N);

    // ---- decoder ----
    matmul_kernel<64, true><<<dim3(gx, 2), 256, 0, stream>>>(Zbf, W_d1, Hbf,
                                                             N);      // Y2
    agg_kernel<true><<<aggBlocks, 256, 0, stream>>>(Hbf, offs, esrc, dinv,
                                                    b_d1, Ybf, N);    // hd
    matmul_kernel<128, true><<<dim3(gx, 2), 256, 0, stream>>>(Ybf, W_d2, Hbf,
                                                              N);     // Y3
    agg_kernel<false><<<aggBlocks, 256, 0, stream>>>(Hbf, offs, esrc, dinv,
                                                     b_d2, gout, N);  // out
}